// Round 4
// baseline (497.037 us; speedup 1.0000x reference)
//
#include <hip/hip_runtime.h>

// ---------------------------------------------------------------------------
// Fused MultiHeadAttention forward for MI355X (gfx950).  Round 4.
//   B=4, S=2048, D_MODEL=1024, H=16, depth=64
// Round-4 changes:
//  - GEMMs back to bf16 A (cvt_one pass restored): halves K-loop HBM bytes
//    and makes the per-XCD working set (8 m-tiles A + B = 4MB) fit XCD L2.
//  - attn: 64 q-rows/wave (halves K/V LDS traffic + barriers per score),
//    P-LDS stride 68 (conflict-free b16 writes), P reads via ds_read_b64.
// ---------------------------------------------------------------------------

typedef __bf16 bf16_t;
typedef __bf16 bf16x4 __attribute__((ext_vector_type(4)));
typedef __bf16 bf16x8 __attribute__((ext_vector_type(8)));
typedef float floatx4 __attribute__((ext_vector_type(4)));

#define DMODEL 1024
#define NHEAD  16
#define DEPTH  64
#define BATCH  4
#define SEQ    2048
#define MROWS  (BATCH * SEQ)   // 8192

// exp(s) = exp2(s*log2e); fold log2(e)/8 into Wq so QK^T acc is exp2-ready
#define QSCALE 0.18033688011112042f

#define GLDS16(gaddr, laddr)                                                   \
  __builtin_amdgcn_global_load_lds(                                            \
      (__attribute__((address_space(1))) void*)(gaddr),                        \
      (__attribute__((address_space(3))) void*)(laddr), 16, 0, 0)

// ---------------------------------------------------------------------------
// fp32 -> bf16 for the 4 weight matrices, Wq pre-scaled by QSCALE.
// ---------------------------------------------------------------------------
__global__ __launch_bounds__(256) void cvt_weights(
    const float* __restrict__ w0, const float* __restrict__ w1,
    const float* __restrict__ w2, const float* __restrict__ w3,
    bf16_t* __restrict__ out) {
  const int n_per4 = (DMODEL * DMODEL) / 4;
  int idx = blockIdx.x * blockDim.x + threadIdx.x;
  int t = idx / n_per4;
  int e4 = idx - t * n_per4;
  const float* src = (t == 0) ? w0 : (t == 1) ? w1 : (t == 2) ? w2 : w3;
  const float sc = (t == 0) ? QSCALE : 1.0f;
  float4 v = ((const float4*)src)[e4];
  bf16_t* dst = out + (size_t)t * (DMODEL * DMODEL) + (size_t)e4 * 4;
  dst[0] = (bf16_t)(v.x * sc); dst[1] = (bf16_t)(v.y * sc);
  dst[2] = (bf16_t)(v.z * sc); dst[3] = (bf16_t)(v.w * sc);
}

// ---------------------------------------------------------------------------
// fp32 -> bf16 for one activation tensor (8 elements/thread).
// ---------------------------------------------------------------------------
__global__ __launch_bounds__(256) void cvt_one(
    const float* __restrict__ src, bf16_t* __restrict__ dst) {
  size_t i = (size_t)blockIdx.x * blockDim.x + threadIdx.x;  // MROWS*DMODEL/8
  const float4* s = (const float4*)(src + i * 8);
  float4 f0 = s[0], f1 = s[1];
  bf16x8 o;
  o[0] = (bf16_t)f0.x; o[1] = (bf16_t)f0.y; o[2] = (bf16_t)f0.z; o[3] = (bf16_t)f0.w;
  o[4] = (bf16_t)f1.x; o[5] = (bf16_t)f1.y; o[6] = (bf16_t)f1.z; o[7] = (bf16_t)f1.w;
  *(bf16x8*)(dst + i * 8) = o;
}

// ---------------------------------------------------------------------------
// Mask -> per-lane u32 KEEP-bit words (bit=1 means keep):
//   word[((b*64 + g)*32 + it)*64 + lane], bit ((mi*4+r)*4+ni) = 1 iff
//   m_in[b][q = g*32 + mi*16 + (lane>>4)*4 + r][k = it*64 + ni*16 + (lane&15)] == 0
// (g indexes 32-row q-groups; attn consumes two consecutive g's per wave.)
// ---------------------------------------------------------------------------
__global__ __launch_bounds__(256) void mask_prepack(
    const float* __restrict__ m, unsigned int* __restrict__ M32) {
  size_t t = (size_t)blockIdx.x * blockDim.x + threadIdx.x;  // 4*64*32*64
  int lane = t & 63;
  int it = (t >> 6) & 31;
  int g  = (t >> 11) & 63;
  int b  = (int)(t >> 17);
  int quad = lane >> 4, l16 = lane & 15;
  unsigned int bits = 0;
#pragma unroll
  for (int mi = 0; mi < 2; mi++) {
#pragma unroll
    for (int r = 0; r < 4; r++) {
      const int q = g * 32 + mi * 16 + quad * 4 + r;
      const float* row = m + ((size_t)b * SEQ + q) * SEQ + it * 64 + l16;
#pragma unroll
      for (int ni = 0; ni < 4; ni++) {
        if (row[ni * 16] == 0.f) bits |= 1u << ((mi * 4 + r) * 4 + ni);
      }
    }
  }
  M32[t] = bits;
}

// ---------------------------------------------------------------------------
// GEMM: Y[m,n] = sum_k A[m,k]*Bt[n,k] + bias_scale*bias[n]   (A bf16)
// 256 thr / 4 waves, 128x128 tile, BK=32, global_load_lds(16B), XOR swizzle.
// OMODE: 0 bf16 [B,H,S,64] | 1 bf16 [B,H,64,S] (V^T) | 2 fp32 [M,N]
// Grid MUST be (8,64). XCD swizzle: XCD c hosts 8 m-tiles x all 8 n-tiles;
// per-XCD L2 set = 8*256KB A + 2MB B = 4MB (fits 4MiB XCD L2).
// ---------------------------------------------------------------------------
template <int OMODE>
__global__ __launch_bounds__(256) void gemm128(
    const bf16_t* __restrict__ A, const bf16_t* __restrict__ Bt,
    const float* __restrict__ bias, float bias_scale, void* __restrict__ Ov,
    int M, int N, int K) {
  __shared__ __align__(16) bf16_t As[128 * 32];
  __shared__ __align__(16) bf16_t Bs[128 * 32];
  const int tid = threadIdx.x;
  const int lane = tid & 63;
  const int w = tid >> 6;
  const int quad = lane >> 4;
  const int l16 = lane & 15;
  const int wm = w & 1, wn = w >> 1;

  const int lin = blockIdx.x + 8 * blockIdx.y;   // grid (8,64)
  const int c = lin & 7;
  const int j = lin >> 3;            // 0..63
  const int n0 = (j & 7) * 128;
  const int m0 = ((j >> 3) * 8 + c) * 128;

  // staging: per wave 32 rows in 2 insts of 16 rows; 16B chunks XOR-swizzled
  const int r4 = lane >> 2;                 // 0..15
  const int c4 = (lane & 3) ^ (r4 & 3);     // swizzled chunk
  const bf16_t* Ag = A + (size_t)(m0 + w * 32 + r4) * K + c4 * 8;
  const bf16_t* Bg = Bt + (size_t)(n0 + w * 32 + r4) * K + c4 * 8;
  char* AsB = (char*)As + (w * 32) * 64;
  char* BsB = (char*)Bs + (w * 32) * 64;

  floatx4 acc[4][4] = {};

  for (int kk = 0; kk < K; kk += 32) {
    __syncthreads();
    GLDS16(Ag + kk, AsB);
    GLDS16(Ag + kk + (size_t)16 * K, AsB + 16 * 64);
    GLDS16(Bg + kk, BsB);
    GLDS16(Bg + kk + (size_t)16 * K, BsB + 16 * 64);
    __syncthreads();

    bf16x8 af[4], bfr[4];
#pragma unroll
    for (int mi = 0; mi < 4; mi++) {
      const char* Arow = (const char*)As + (wm * 64 + mi * 16 + l16) * 64;
      af[mi] = *(const bf16x8*)(Arow + ((quad ^ (l16 & 3)) * 16));
    }
#pragma unroll
    for (int ni = 0; ni < 4; ni++) {
      const char* Brow = (const char*)Bs + (wn * 64 + ni * 16 + l16) * 64;
      bfr[ni] = *(const bf16x8*)(Brow + ((quad ^ (l16 & 3)) * 16));
    }
#pragma unroll
    for (int mi = 0; mi < 4; mi++)
#pragma unroll
      for (int ni = 0; ni < 4; ni++)
        acc[mi][ni] = __builtin_amdgcn_mfma_f32_16x16x32_bf16(af[mi], bfr[ni], acc[mi][ni], 0, 0, 0);
  }

#pragma unroll
  for (int ni = 0; ni < 4; ni++) {
    const int col = n0 + wn * 64 + ni * 16 + l16;
    const float bv = bias_scale * bias[col];
#pragma unroll
    for (int mi = 0; mi < 4; mi++) {
#pragma unroll
      for (int r = 0; r < 4; r++) {
        const int row = m0 + wm * 64 + mi * 16 + quad * 4 + r;
        const float val = acc[mi][ni][r] + bv;
        if (OMODE == 0) {
          const int b = row >> 11, s = row & (SEQ - 1);
          const int h = col >> 6, d = col & (DEPTH - 1);
          ((bf16_t*)Ov)[((((size_t)b * NHEAD + h) * SEQ + s) << 6) + d] = (bf16_t)val;
        } else if (OMODE == 1) {
          const int b = row >> 11, s = row & (SEQ - 1);
          const int h = col >> 6, d = col & (DEPTH - 1);
          ((bf16_t*)Ov)[(((size_t)b * NHEAD + h) * DEPTH + d) * SEQ + s] = (bf16_t)val;
        } else {
          ((float*)Ov)[(size_t)row * N + col] = val;
        }
      }
    }
  }
}

// ---------------------------------------------------------------------------
// Attention. 1 block (4 waves) per (b, h, 256 q-rows); wave owns 64 q-rows.
// Per 64-key tile: cooperative K/V LDS staging, QK^T per 16-key group ->
// exp2 -> keep-bit AND -> P via wave-private LDS (stride 68, b64 reads) -> PV.
// XCD swizzle: XCD hosts 8 (b,h) pairs x 8 q-tiles -> K/V set 4MB in L2.
// ---------------------------------------------------------------------------
__global__ __launch_bounds__(256) void attn_kernel(
    const bf16_t* __restrict__ Qh, const bf16_t* __restrict__ Kh,
    const bf16_t* __restrict__ Vt, const unsigned int* __restrict__ M32,
    bf16_t* __restrict__ O) {
  const int lane = threadIdx.x & 63;
  const int w = __builtin_amdgcn_readfirstlane(threadIdx.x >> 6);
  const int quad = lane >> 4;
  const int l16 = lane & 15;

  const int lin = blockIdx.x + 8 * (blockIdx.y + 16 * blockIdx.z);  // 0..511
  const int c = lin & 7;
  const int j = lin >> 3;            // 0..63
  const int p = (j & 7) * 8 + c;     // (b,h) pair: XCD c hosts p%8==c
  const int qt = j >> 3;             // 0..7
  const int h = p & 15;
  const int b = p >> 4;
  const int q0 = qt * 256;

  const bf16_t* Qb = Qh + ((size_t)b * NHEAD + h) * SEQ * DEPTH;
  const bf16_t* Kb = Kh + ((size_t)b * NHEAD + h) * SEQ * DEPTH;
  const bf16_t* Vb = Vt + ((size_t)b * NHEAD + h) * DEPTH * SEQ;
  // two 32-row mask groups per wave: g0 = qt*8 + w*2, g0+1
  const unsigned int* Mw0 =
      M32 + ((size_t)b * 64 + (qt * 8 + w * 2)) * 32 * 64 + lane;
  const unsigned int* Mw1 = Mw0 + 32 * 64;

  __shared__ __align__(16) bf16_t Ksm[64 * 64];   // [key][depth], swizzled
  __shared__ __align__(16) bf16_t Vsm[64 * 64];   // [depth][key], swizzled
  __shared__ __align__(16) bf16_t Pw[4][64][68];  // wave-private, stride 68

  const int r8 = lane >> 3;             // 0..7
  const int c8 = (lane & 7) ^ r8;       // swizzled 16B chunk
  const bf16_t* Kg = Kb + (size_t)(w * 16 + r8) * DEPTH + c8 * 8;
  const bf16_t* Vg = Vb + (size_t)(w * 16 + r8) * SEQ + c8 * 8;
  char* KsB = (char*)Ksm + (w * 16) * 128;
  char* VsB = (char*)Vsm + (w * 16) * 128;

  // Q fragments: q = q0 + w*64 + mi*16 + l16, d = kb*32 + quad*8
  bf16x8 aq[4][2];
#pragma unroll
  for (int mi = 0; mi < 4; mi++) {
    const bf16_t* qp = Qb + (size_t)(q0 + w * 64 + mi * 16 + l16) * DEPTH + quad * 8;
    aq[mi][0] = *(const bf16x8*)qp;
    aq[mi][1] = *(const bf16x8*)(qp + 32);
  }

  floatx4 acco[4][4] = {};
  float lsum[4][4] = {};
  const int swz = l16 & 7;

  for (int it = 0; it < SEQ / 64; ++it) {
    const int sk = it * 64;
    __syncthreads();
    GLDS16(Kg + (size_t)sk * DEPTH, KsB);
    GLDS16(Kg + (size_t)sk * DEPTH + 8 * DEPTH, KsB + 8 * 128);
    GLDS16(Vg + sk, VsB);
    GLDS16(Vg + sk + (size_t)8 * SEQ, VsB + 8 * 128);
    __syncthreads();

    const unsigned int mw0 = Mw0[it * 64];
    const unsigned int mw1 = Mw1[it * 64];

    // ---- per 16-key group: QK^T, exp2, mask, P-write ----
#pragma unroll
    for (int ni = 0; ni < 4; ni++) {
      const char* Krow = (const char*)Ksm + (ni * 16 + l16) * 128;
      bf16x8 k0 = *(const bf16x8*)(Krow + ((quad ^ swz) * 16));
      bf16x8 k1 = *(const bf16x8*)(Krow + (((4 + quad) ^ swz) * 16));
      floatx4 s[4];
#pragma unroll
      for (int mi = 0; mi < 4; mi++) {
        floatx4 z = {};
        z = __builtin_amdgcn_mfma_f32_16x16x32_bf16(aq[mi][0], k0, z, 0, 0, 0);
        s[mi] = __builtin_amdgcn_mfma_f32_16x16x32_bf16(aq[mi][1], k1, z, 0, 0, 0);
      }
#pragma unroll
      for (int mi = 0; mi < 4; mi++) {
        const unsigned int mword = (mi < 2) ? mw0 : mw1;
        const int mb = (mi & 1) * 16;
#pragma unroll
        for (int r = 0; r < 4; r++) {
          float pv = __builtin_amdgcn_exp2f(s[mi][r]);
          const int idx = mb + r * 4 + ni;
          const int km = ((int)(mword << (31 - idx))) >> 31;  // keep ? -1 : 0
          pv = __int_as_float(__float_as_int(pv) & km);
          lsum[mi][r] += pv;
          Pw[w][mi * 16 + quad * 4 + r][ni * 16 + l16] = (bf16_t)pv;
        }
      }
    }

    // ---- P reads (A-layout) as paired ds_read_b64 (rows are 8B-aligned) ----
    bf16x8 pa[4][2];
#pragma unroll
    for (int mi = 0; mi < 4; mi++) {
#pragma unroll
      for (int kb = 0; kb < 2; kb++) {
        const bf16_t* pp = &Pw[w][mi * 16 + l16][kb * 32 + quad * 8];
        bf16x4 lo = *(const bf16x4*)pp;
        bf16x4 hi = *(const bf16x4*)(pp + 4);
        pa[mi][kb] = __builtin_shufflevector(lo, hi, 0, 1, 2, 3, 4, 5, 6, 7);
      }
    }
    // ---- PV ----
#pragma unroll
    for (int ni = 0; ni < 4; ni++) {
      const char* Vrow = (const char*)Vsm + (ni * 16 + l16) * 128;
#pragma unroll
      for (int kb = 0; kb < 2; kb++) {
        bf16x8 vb = *(const bf16x8*)(Vrow + ((((kb * 4) + quad) ^ swz) * 16));
#pragma unroll
        for (int mi = 0; mi < 4; mi++)
          acco[mi][ni] = __builtin_amdgcn_mfma_f32_16x16x32_bf16(pa[mi][kb], vb, acco[mi][ni], 0, 0, 0);
      }
    }
  }

  // ---- epilogue ----
  float inv_l[4][4];
#pragma unroll
  for (int mi = 0; mi < 4; mi++)
#pragma unroll
    for (int r = 0; r < 4; r++) {
      float s = lsum[mi][r];
      s += __shfl_xor(s, 1);
      s += __shfl_xor(s, 2);
      s += __shfl_xor(s, 4);
      s += __shfl_xor(s, 8);
      inv_l[mi][r] = __frcp_rn(s);
    }

#pragma unroll
  for (int mi = 0; mi < 4; mi++)
#pragma unroll
    for (int ni = 0; ni < 4; ni++)
#pragma unroll
      for (int r = 0; r < 4; r++) {
        const int s = q0 + w * 64 + mi * 16 + quad * 4 + r;
        const int d = h * DEPTH + ni * 16 + l16;
        O[((size_t)b * SEQ + s) * DMODEL + d] = (bf16_t)(acco[mi][ni][r] * inv_l[mi][r]);
      }
}

// ---------------------------------------------------------------------------
extern "C" void kernel_launch(void* const* d_in, const int* in_sizes, int n_in,
                              void* d_out, int out_size, void* d_ws, size_t ws_size,
                              hipStream_t stream) {
  const float* q_in = (const float*)d_in[0];
  const float* k_in = (const float*)d_in[1];
  const float* v_in = (const float*)d_in[2];
  const float* m_in = (const float*)d_in[3];
  const float* Wq = (const float*)d_in[4];
  const float* bq = (const float*)d_in[5];
  const float* Wk = (const float*)d_in[6];
  const float* bk = (const float*)d_in[7];
  const float* Wv = (const float*)d_in[8];
  const float* bv = (const float*)d_in[9];
  const float* Wo = (const float*)d_in[10];
  const float* bo = (const float*)d_in[11];

  // workspace:
  //   [0,  8MB) : bf16 weights Wq|Wk|Wv|Wo
  //   [8, 24MB) : Abf (per-GEMM bf16 input) -> later Obuf (stream-ordered)
  //   [24,40MB) : Qh  bf16 [B,H,S,64]
  //   [40,56MB) : Kh  bf16 [B,H,S,64]
  //   [56,72MB) : Vth bf16 [B,H,64,S]
  //   [72,74MB) : M32 keep-bit words
  char* ws = (char*)d_ws;
  const size_t MB = 1024 * 1024;
  bf16_t* wbf = (bf16_t*)ws;
  bf16_t* Wq_bf = wbf + 0 * (size_t)DMODEL * DMODEL;
  bf16_t* Wk_bf = wbf + 1 * (size_t)DMODEL * DMODEL;
  bf16_t* Wv_bf = wbf + 2 * (size_t)DMODEL * DMODEL;
  bf16_t* Wo_bf = wbf + 3 * (size_t)DMODEL * DMODEL;
  bf16_t* Abf  = (bf16_t*)(ws + 8 * MB);
  bf16_t* Obuf = (bf16_t*)(ws + 8 * MB);
  bf16_t* Qh   = (bf16_t*)(ws + 24 * MB);
  bf16_t* Kh   = (bf16_t*)(ws + 40 * MB);
  bf16_t* Vth  = (bf16_t*)(ws + 56 * MB);
  unsigned int* M32 = (unsigned int*)(ws + 72 * MB);

  cvt_weights<<<(4 * (DMODEL * DMODEL / 4)) / 256, 256, 0, stream>>>(
      Wq, Wk, Wv, Wo, wbf);
  mask_prepack<<<(BATCH * 64 * 32 * 64) / 256, 256, 0, stream>>>(m_in, M32);

  dim3 gg(DMODEL / 128, MROWS / 128);  // (8, 64)
  const int cvt_blocks = (MROWS * DMODEL / 8) / 256;

  cvt_one<<<cvt_blocks, 256, 0, stream>>>(q_in, Abf);
  gemm128<0><<<gg, 256, 0, stream>>>(Abf, Wq_bf, bq, QSCALE, Qh, MROWS, DMODEL, DMODEL);
  cvt_one<<<cvt_blocks, 256, 0, stream>>>(k_in, Abf);
  gemm128<0><<<gg, 256, 0, stream>>>(Abf, Wk_bf, bk, 1.0f, Kh, MROWS, DMODEL, DMODEL);
  cvt_one<<<cvt_blocks, 256, 0, stream>>>(v_in, Abf);
  gemm128<1><<<gg, 256, 0, stream>>>(Abf, Wv_bf, bv, 1.0f, Vth, MROWS, DMODEL, DMODEL);

  dim3 ga(SEQ / 256, NHEAD, BATCH);  // (8,16,4)
  attn_kernel<<<ga, 256, 0, stream>>>(Qh, Kh, Vth, M32, Obuf);

  gemm128<2><<<gg, 256, 0, stream>>>(Obuf, Wo_bf, bo, 1.0f, d_out, MROWS, DMODEL, DMODEL);
}

// Round 5
// 438.565 us; speedup vs baseline: 1.1333x; 1.1333x over previous
//
#include <hip/hip_runtime.h>

// ---------------------------------------------------------------------------
// Fused MultiHeadAttention forward for MI355X (gfx950).  Round 5.
//   B=4, S=2048, D_MODEL=1024, H=16, depth=64
// Round-5 changes:
//  - attn reverted to round-3 shape (128q/block, 32q/wave -> occ ~35%) but
//    with round-4's conflict-free P LDS (stride 68, paired b64 reads).
//  - Q/K/V projections merged into ONE dispatch (grid 8x64x3 = 1536 blocks,
//    6 blocks/CU queued) to hide the per-iter barrier drain; one cvt pass
//    converts all three fp32 inputs to bf16.
// ---------------------------------------------------------------------------

typedef __bf16 bf16_t;
typedef __bf16 bf16x4 __attribute__((ext_vector_type(4)));
typedef __bf16 bf16x8 __attribute__((ext_vector_type(8)));
typedef float floatx4 __attribute__((ext_vector_type(4)));

#define DMODEL 1024
#define NHEAD  16
#define DEPTH  64
#define BATCH  4
#define SEQ    2048
#define MROWS  (BATCH * SEQ)   // 8192

// exp(s) = exp2(s*log2e); fold log2(e)/8 into Wq (and bq) so QK^T is exp2-ready
#define QSCALE 0.18033688011112042f

#define GLDS16(gaddr, laddr)                                                   \
  __builtin_amdgcn_global_load_lds(                                            \
      (__attribute__((address_space(1))) void*)(gaddr),                        \
      (__attribute__((address_space(3))) void*)(laddr), 16, 0, 0)

// ---------------------------------------------------------------------------
// fp32 -> bf16 for the 4 weight matrices, Wq pre-scaled by QSCALE.
// ---------------------------------------------------------------------------
__global__ __launch_bounds__(256) void cvt_weights(
    const float* __restrict__ w0, const float* __restrict__ w1,
    const float* __restrict__ w2, const float* __restrict__ w3,
    bf16_t* __restrict__ out) {
  const int n_per4 = (DMODEL * DMODEL) / 4;
  int idx = blockIdx.x * blockDim.x + threadIdx.x;
  int t = idx / n_per4;
  int e4 = idx - t * n_per4;
  const float* src = (t == 0) ? w0 : (t == 1) ? w1 : (t == 2) ? w2 : w3;
  const float sc = (t == 0) ? QSCALE : 1.0f;
  float4 v = ((const float4*)src)[e4];
  bf16_t* dst = out + (size_t)t * (DMODEL * DMODEL) + (size_t)e4 * 4;
  dst[0] = (bf16_t)(v.x * sc); dst[1] = (bf16_t)(v.y * sc);
  dst[2] = (bf16_t)(v.z * sc); dst[3] = (bf16_t)(v.w * sc);
}

// ---------------------------------------------------------------------------
// fp32 -> bf16 for the three activation inputs into one 48MB buffer.
// ---------------------------------------------------------------------------
__global__ __launch_bounds__(256) void cvt3(
    const float* __restrict__ q, const float* __restrict__ k,
    const float* __restrict__ v, bf16_t* __restrict__ dst) {
  const size_t n8 = (size_t)MROWS * DMODEL / 8;  // per-tensor 8-elem groups
  size_t i = (size_t)blockIdx.x * blockDim.x + threadIdx.x;  // 3*n8 threads
  int t = (int)(i / n8);
  size_t e = i - (size_t)t * n8;
  const float* src = (t == 0) ? q : (t == 1) ? k : v;
  const float4* s = (const float4*)(src + e * 8);
  float4 f0 = s[0], f1 = s[1];
  bf16x8 o;
  o[0] = (bf16_t)f0.x; o[1] = (bf16_t)f0.y; o[2] = (bf16_t)f0.z; o[3] = (bf16_t)f0.w;
  o[4] = (bf16_t)f1.x; o[5] = (bf16_t)f1.y; o[6] = (bf16_t)f1.z; o[7] = (bf16_t)f1.w;
  *(bf16x8*)(dst + i * 8) = o;
}

// ---------------------------------------------------------------------------
// Mask -> per-lane u32 KEEP-bit words (bit=1 means keep):
//   word[((b*64 + g)*32 + it)*64 + lane], bit ((mi*4+r)*4+ni) = 1 iff
//   m_in[b][q = g*32 + mi*16 + (lane>>4)*4 + r][k = it*64 + ni*16 + (lane&15)] == 0
// ---------------------------------------------------------------------------
__global__ __launch_bounds__(256) void mask_prepack(
    const float* __restrict__ m, unsigned int* __restrict__ M32) {
  size_t t = (size_t)blockIdx.x * blockDim.x + threadIdx.x;  // 4*64*32*64
  int lane = t & 63;
  int it = (t >> 6) & 31;
  int g  = (t >> 11) & 63;
  int b  = (int)(t >> 17);
  int quad = lane >> 4, l16 = lane & 15;
  unsigned int bits = 0;
#pragma unroll
  for (int mi = 0; mi < 2; mi++) {
#pragma unroll
    for (int r = 0; r < 4; r++) {
      const int q = g * 32 + mi * 16 + quad * 4 + r;
      const float* row = m + ((size_t)b * SEQ + q) * SEQ + it * 64 + l16;
#pragma unroll
      for (int ni = 0; ni < 4; ni++) {
        if (row[ni * 16] == 0.f) bits |= 1u << ((mi * 4 + r) * 4 + ni);
      }
    }
  }
  M32[t] = bits;
}

// ---------------------------------------------------------------------------
// Merged QKV GEMM: z = blockIdx.z selects (input, weight, bias, output).
//   Y[m,n] = sum_k A_z[m,k]*W_z[n,k] + bs_z*bias_z[n]
// 256 thr / 4 waves, 128x128 tile, BK=32, global_load_lds(16B), XOR swizzle.
// z<2 -> bf16 out [B,H,S,64] (Q,K); z==2 -> bf16 out [B,H,64,S] (V^T).
// Grid (8,64,3); XCD swizzle groups one m-supertile's 8 n-blocks per XCD.
// ---------------------------------------------------------------------------
__global__ __launch_bounds__(256) void gemm_qkv(
    const bf16_t* __restrict__ Abf3, const bf16_t* __restrict__ Wbf,
    const float* __restrict__ bq, const float* __restrict__ bk,
    const float* __restrict__ bv, bf16_t* __restrict__ Qh,
    bf16_t* __restrict__ Kh, bf16_t* __restrict__ Vth) {
  __shared__ __align__(16) bf16_t As[128 * 32];
  __shared__ __align__(16) bf16_t Bs[128 * 32];
  const int K = DMODEL;
  const int tid = threadIdx.x;
  const int lane = tid & 63;
  const int w = tid >> 6;
  const int quad = lane >> 4;
  const int l16 = lane & 15;
  const int wm = w & 1, wn = w >> 1;
  const int z = blockIdx.z;

  const bf16_t* A = Abf3 + (size_t)z * MROWS * DMODEL;
  const bf16_t* Bt = Wbf + (size_t)z * DMODEL * DMODEL;
  const float* bias = (z == 0) ? bq : (z == 1) ? bk : bv;
  const float bias_scale = (z == 0) ? QSCALE : 1.0f;
  bf16_t* Ov = (z == 0) ? Qh : (z == 1) ? Kh : Vth;

  const int lin = blockIdx.x + 8 * blockIdx.y;   // (8,64) per z
  const int c = lin & 7;
  const int j = lin >> 3;            // 0..63
  const int n0 = (j & 7) * 128;
  const int m0 = ((j >> 3) * 8 + c) * 128;

  const int r4 = lane >> 2;
  const int c4 = (lane & 3) ^ (r4 & 3);
  const bf16_t* Ag = A + (size_t)(m0 + w * 32 + r4) * K + c4 * 8;
  const bf16_t* Bg = Bt + (size_t)(n0 + w * 32 + r4) * K + c4 * 8;
  char* AsB = (char*)As + (w * 32) * 64;
  char* BsB = (char*)Bs + (w * 32) * 64;

  floatx4 acc[4][4] = {};

  for (int kk = 0; kk < K; kk += 32) {
    __syncthreads();
    GLDS16(Ag + kk, AsB);
    GLDS16(Ag + kk + (size_t)16 * K, AsB + 16 * 64);
    GLDS16(Bg + kk, BsB);
    GLDS16(Bg + kk + (size_t)16 * K, BsB + 16 * 64);
    __syncthreads();

    bf16x8 af[4], bfr[4];
#pragma unroll
    for (int mi = 0; mi < 4; mi++) {
      const char* Arow = (const char*)As + (wm * 64 + mi * 16 + l16) * 64;
      af[mi] = *(const bf16x8*)(Arow + ((quad ^ (l16 & 3)) * 16));
    }
#pragma unroll
    for (int ni = 0; ni < 4; ni++) {
      const char* Brow = (const char*)Bs + (wn * 64 + ni * 16 + l16) * 64;
      bfr[ni] = *(const bf16x8*)(Brow + ((quad ^ (l16 & 3)) * 16));
    }
#pragma unroll
    for (int mi = 0; mi < 4; mi++)
#pragma unroll
      for (int ni = 0; ni < 4; ni++)
        acc[mi][ni] = __builtin_amdgcn_mfma_f32_16x16x32_bf16(af[mi], bfr[ni], acc[mi][ni], 0, 0, 0);
  }

#pragma unroll
  for (int ni = 0; ni < 4; ni++) {
    const int col = n0 + wn * 64 + ni * 16 + l16;
    const float bvl = bias_scale * bias[col];
    const int hh = col >> 6, d = col & (DEPTH - 1);
#pragma unroll
    for (int mi = 0; mi < 4; mi++) {
#pragma unroll
      for (int r = 0; r < 4; r++) {
        const int row = m0 + wm * 64 + mi * 16 + quad * 4 + r;
        const float val = acc[mi][ni][r] + bvl;
        const int bb = row >> 11, s = row & (SEQ - 1);
        if (z != 2) {
          Ov[((((size_t)bb * NHEAD + hh) * SEQ + s) << 6) + d] = (bf16_t)val;
        } else {
          Ov[(((size_t)bb * NHEAD + hh) * DEPTH + d) * SEQ + s] = (bf16_t)val;
        }
      }
    }
  }
}

// ---------------------------------------------------------------------------
// Output-projection GEMM (A bf16, fp32 out [M,N]).  Grid (8,64).
// ---------------------------------------------------------------------------
__global__ __launch_bounds__(256) void gemm_wo(
    const bf16_t* __restrict__ A, const bf16_t* __restrict__ Bt,
    const float* __restrict__ bias, float* __restrict__ Ov,
    int M, int N, int K) {
  __shared__ __align__(16) bf16_t As[128 * 32];
  __shared__ __align__(16) bf16_t Bs[128 * 32];
  const int tid = threadIdx.x;
  const int lane = tid & 63;
  const int w = tid >> 6;
  const int quad = lane >> 4;
  const int l16 = lane & 15;
  const int wm = w & 1, wn = w >> 1;

  const int lin = blockIdx.x + 8 * blockIdx.y;
  const int c = lin & 7;
  const int j = lin >> 3;
  const int n0 = (j & 7) * 128;
  const int m0 = ((j >> 3) * 8 + c) * 128;

  const int r4 = lane >> 2;
  const int c4 = (lane & 3) ^ (r4 & 3);
  const bf16_t* Ag = A + (size_t)(m0 + w * 32 + r4) * K + c4 * 8;
  const bf16_t* Bg = Bt + (size_t)(n0 + w * 32 + r4) * K + c4 * 8;
  char* AsB = (char*)As + (w * 32) * 64;
  char* BsB = (char*)Bs + (w * 32) * 64;

  floatx4 acc[4][4] = {};

  for (int kk = 0; kk < K; kk += 32) {
    __syncthreads();
    GLDS16(Ag + kk, AsB);
    GLDS16(Ag + kk + (size_t)16 * K, AsB + 16 * 64);
    GLDS16(Bg + kk, BsB);
    GLDS16(Bg + kk + (size_t)16 * K, BsB + 16 * 64);
    __syncthreads();

    bf16x8 af[4], bfr[4];
#pragma unroll
    for (int mi = 0; mi < 4; mi++) {
      const char* Arow = (const char*)As + (wm * 64 + mi * 16 + l16) * 64;
      af[mi] = *(const bf16x8*)(Arow + ((quad ^ (l16 & 3)) * 16));
    }
#pragma unroll
    for (int ni = 0; ni < 4; ni++) {
      const char* Brow = (const char*)Bs + (wn * 64 + ni * 16 + l16) * 64;
      bfr[ni] = *(const bf16x8*)(Brow + ((quad ^ (l16 & 3)) * 16));
    }
#pragma unroll
    for (int mi = 0; mi < 4; mi++)
#pragma unroll
      for (int ni = 0; ni < 4; ni++)
        acc[mi][ni] = __builtin_amdgcn_mfma_f32_16x16x32_bf16(af[mi], bfr[ni], acc[mi][ni], 0, 0, 0);
  }

#pragma unroll
  for (int ni = 0; ni < 4; ni++) {
    const int col = n0 + wn * 64 + ni * 16 + l16;
    const float bv = bias[col];
#pragma unroll
    for (int mi = 0; mi < 4; mi++)
#pragma unroll
      for (int r = 0; r < 4; r++) {
        const int row = m0 + wm * 64 + mi * 16 + quad * 4 + r;
        Ov[(size_t)row * N + col] = acc[mi][ni][r] + bv;
      }
  }
}

// ---------------------------------------------------------------------------
// Attention (round-3 shape + conflict-free P). 1 block (4 waves) per
// (b, h, 128 q-rows); wave owns 32 q-rows. Per 64-key tile: cooperative K/V
// LDS staging (swizzled), QK^T -> exp2 -> keep-bit AND -> P (stride-68 LDS,
// b64 reads) -> PV. XCD swizzle: head's 16 q-blocks share an XCD.
// ---------------------------------------------------------------------------
__global__ __launch_bounds__(256) void attn_kernel(
    const bf16_t* __restrict__ Qh, const bf16_t* __restrict__ Kh,
    const bf16_t* __restrict__ Vt, const unsigned int* __restrict__ M32,
    bf16_t* __restrict__ O) {
  const int lane = threadIdx.x & 63;
  const int w = __builtin_amdgcn_readfirstlane(threadIdx.x >> 6);
  const int quad = lane >> 4;
  const int l16 = lane & 15;

  const int lin = blockIdx.x + 16 * blockIdx.y + 256 * blockIdx.z;  // 0..1023
  const int x8 = lin & 7;
  const int kk = lin >> 3;           // 0..127
  const int qt = kk & 15;            // q-tile
  const int p = ((kk >> 4) << 3) | x8;  // (b,h) pair
  const int h = p & 15;
  const int b = p >> 4;
  const int q0 = qt * 128;

  const bf16_t* Qb = Qh + ((size_t)b * NHEAD + h) * SEQ * DEPTH;
  const bf16_t* Kb = Kh + ((size_t)b * NHEAD + h) * SEQ * DEPTH;
  const bf16_t* Vb = Vt + ((size_t)b * NHEAD + h) * DEPTH * SEQ;
  const unsigned int* Mw =
      M32 + ((size_t)b * 64 + (qt * 4 + w)) * 32 * 64 + lane;

  __shared__ __align__(16) bf16_t Ksm[64 * 64];   // [key][depth], swizzled
  __shared__ __align__(16) bf16_t Vsm[64 * 64];   // [depth][key], swizzled
  __shared__ __align__(16) bf16_t Pw[4][32][68];  // wave-private, stride 68

  const int r8 = lane >> 3;
  const int c8 = (lane & 7) ^ r8;
  const bf16_t* Kg = Kb + (size_t)(w * 16 + r8) * DEPTH + c8 * 8;
  const bf16_t* Vg = Vb + (size_t)(w * 16 + r8) * SEQ + c8 * 8;
  char* KsB = (char*)Ksm + (w * 16) * 128;
  char* VsB = (char*)Vsm + (w * 16) * 128;

  bf16x8 aq[2][2];
#pragma unroll
  for (int mi = 0; mi < 2; mi++) {
    const bf16_t* qp = Qb + (size_t)(q0 + w * 32 + mi * 16 + l16) * DEPTH + quad * 8;
    aq[mi][0] = *(const bf16x8*)qp;
    aq[mi][1] = *(const bf16x8*)(qp + 32);
  }

  floatx4 acco[2][4] = {};
  float lsum[2][4] = {};
  const int swz = l16 & 7;

  for (int it = 0; it < SEQ / 64; ++it) {
    const int sk = it * 64;
    __syncthreads();
    GLDS16(Kg + (size_t)sk * DEPTH, KsB);
    GLDS16(Kg + (size_t)sk * DEPTH + 8 * DEPTH, KsB + 8 * 128);
    GLDS16(Vg + sk, VsB);
    GLDS16(Vg + sk + (size_t)8 * SEQ, VsB + 8 * 128);
    __syncthreads();

    const unsigned int mword = Mw[it * 64];

    // ---- per 16-key group: QK^T, exp2, mask, P-write ----
#pragma unroll
    for (int ni = 0; ni < 4; ni++) {
      const char* Krow = (const char*)Ksm + (ni * 16 + l16) * 128;
      bf16x8 k0 = *(const bf16x8*)(Krow + ((quad ^ swz) * 16));
      bf16x8 k1 = *(const bf16x8*)(Krow + (((4 + quad) ^ swz) * 16));
      floatx4 s[2];
#pragma unroll
      for (int mi = 0; mi < 2; mi++) {
        floatx4 z = {};
        z = __builtin_amdgcn_mfma_f32_16x16x32_bf16(aq[mi][0], k0, z, 0, 0, 0);
        s[mi] = __builtin_amdgcn_mfma_f32_16x16x32_bf16(aq[mi][1], k1, z, 0, 0, 0);
      }
#pragma unroll
      for (int mi = 0; mi < 2; mi++) {
#pragma unroll
        for (int r = 0; r < 4; r++) {
          float pv = __builtin_amdgcn_exp2f(s[mi][r]);
          const int idx = (mi * 4 + r) * 4 + ni;
          const int km = ((int)(mword << (31 - idx))) >> 31;  // keep ? -1 : 0
          pv = __int_as_float(__float_as_int(pv) & km);
          lsum[mi][r] += pv;
          Pw[w][mi * 16 + quad * 4 + r][ni * 16 + l16] = (bf16_t)pv;
        }
      }
    }

    // ---- P reads (A-layout) as paired b64 (rows 8B-aligned, stride 136B) --
    bf16x8 pa[2][2];
#pragma unroll
    for (int mi = 0; mi < 2; mi++) {
#pragma unroll
      for (int kb = 0; kb < 2; kb++) {
        const bf16_t* pp = &Pw[w][mi * 16 + l16][kb * 32 + quad * 8];
        bf16x4 lo = *(const bf16x4*)pp;
        bf16x4 hi = *(const bf16x4*)(pp + 4);
        pa[mi][kb] = __builtin_shufflevector(lo, hi, 0, 1, 2, 3, 4, 5, 6, 7);
      }
    }
    // ---- PV ----
#pragma unroll
    for (int ni = 0; ni < 4; ni++) {
      const char* Vrow = (const char*)Vsm + (ni * 16 + l16) * 128;
#pragma unroll
      for (int kb = 0; kb < 2; kb++) {
        bf16x8 vb = *(const bf16x8*)(Vrow + ((((kb * 4) + quad) ^ swz) * 16));
#pragma unroll
        for (int mi = 0; mi < 2; mi++)
          acco[mi][ni] = __builtin_amdgcn_mfma_f32_16x16x32_bf16(pa[mi][kb], vb, acco[mi][ni], 0, 0, 0);
      }
    }
  }

  // ---- epilogue ----
  float inv_l[2][4];
#pragma unroll
  for (int mi = 0; mi < 2; mi++)
#pragma unroll
    for (int r = 0; r < 4; r++) {
      float s = lsum[mi][r];
      s += __shfl_xor(s, 1);
      s += __shfl_xor(s, 2);
      s += __shfl_xor(s, 4);
      s += __shfl_xor(s, 8);
      inv_l[mi][r] = __frcp_rn(s);
    }

#pragma unroll
  for (int mi = 0; mi < 2; mi++)
#pragma unroll
    for (int ni = 0; ni < 4; ni++)
#pragma unroll
      for (int r = 0; r < 4; r++) {
        const int s = q0 + w * 32 + mi * 16 + quad * 4 + r;
        const int d = h * DEPTH + ni * 16 + l16;
        O[((size_t)b * SEQ + s) * DMODEL + d] = (bf16_t)(acco[mi][ni][r] * inv_l[mi][r]);
      }
}

// ---------------------------------------------------------------------------
extern "C" void kernel_launch(void* const* d_in, const int* in_sizes, int n_in,
                              void* d_out, int out_size, void* d_ws, size_t ws_size,
                              hipStream_t stream) {
  const float* q_in = (const float*)d_in[0];
  const float* k_in = (const float*)d_in[1];
  const float* v_in = (const float*)d_in[2];
  const float* m_in = (const float*)d_in[3];
  const float* Wq = (const float*)d_in[4];
  const float* bq = (const float*)d_in[5];
  const float* Wk = (const float*)d_in[6];
  const float* bk = (const float*)d_in[7];
  const float* Wv = (const float*)d_in[8];
  const float* bv = (const float*)d_in[9];
  const float* Wo = (const float*)d_in[10];
  const float* bo = (const float*)d_in[11];

  // workspace layout:
  //   [0,   8MB) : bf16 weights Wq|Wk|Wv|Wo
  //   [8,  56MB) : Abf3 (3 x 16MB bf16 activations); first 16MB reused as
  //                Obuf after the QKV GEMMs complete (stream-ordered)
  //   [56, 72MB) : Qh  bf16 [B,H,S,64]
  //   [72, 88MB) : Kh  bf16 [B,H,S,64]
  //   [88,104MB) : Vth bf16 [B,H,64,S]
  //   [104,106MB): M32 keep-bit words
  char* ws = (char*)d_ws;
  const size_t MB = 1024 * 1024;
  bf16_t* wbf  = (bf16_t*)ws;
  bf16_t* Abf3 = (bf16_t*)(ws + 8 * MB);
  bf16_t* Obuf = (bf16_t*)(ws + 8 * MB);   // aliases Abf3[0] (safe: QKV done)
  bf16_t* Qh   = (bf16_t*)(ws + 56 * MB);
  bf16_t* Kh   = (bf16_t*)(ws + 72 * MB);
  bf16_t* Vth  = (bf16_t*)(ws + 88 * MB);
  unsigned int* M32 = (unsigned int*)(ws + 104 * MB);

  cvt_weights<<<(4 * (DMODEL * DMODEL / 4)) / 256, 256, 0, stream>>>(
      Wq, Wk, Wv, Wo, wbf);
  cvt3<<<(3 * (MROWS * DMODEL / 8)) / 256, 256, 0, stream>>>(
      q_in, k_in, v_in, Abf3);
  mask_prepack<<<(BATCH * 64 * 32 * 64) / 256, 256, 0, stream>>>(m_in, M32);

  dim3 gqkv(8, 64, 3);
  gemm_qkv<<<gqkv, 256, 0, stream>>>(Abf3, wbf, bq, bk, bv, Qh, Kh, Vth);

  dim3 ga(SEQ / 128, NHEAD, BATCH);  // (16,16,4)
  attn_kernel<<<ga, 256, 0, stream>>>(Qh, Kh, Vth, M32, Obuf);

  dim3 gg(8, 64);
  gemm_wo<<<gg, 256, 0, stream>>>(
      Obuf, wbf + 3 * (size_t)DMODEL * DMODEL, bo, (float*)d_out,
      MROWS, DMODEL, DMODEL);
}